// Round 4
// baseline (527.546 us; speedup 1.0000x reference)
//
#include <hip/hip_runtime.h>

#define NEG 1000000000000.0f

typedef __attribute__((ext_vector_type(4))) float f32x4;
typedef __attribute__((ext_vector_type(8))) short bf16x8;

__device__ __forceinline__ unsigned short f2bf(float f) {
    union { float f; unsigned u; } a;
    a.f = f;
    unsigned u = a.u;
    return (unsigned short)((u + 0x7FFFu + ((u >> 16) & 1u)) >> 16);
}

// async global->LDS, 16B per lane, wave-uniform LDS base
__device__ __forceinline__ void gload_lds16(const void* g, void* l) {
    __builtin_amdgcn_global_load_lds(
        (const __attribute__((address_space(1))) unsigned int*)g,
        (__attribute__((address_space(3))) unsigned int*)l, 16, 0, 0);
}

// ---------------- kernel 0a: fp32 -> bf16 convert (hidden_states) ----------
__global__ void cvt_bf16_kernel(const float* __restrict__ in,
                                unsigned short* __restrict__ out, int n4) {
    int i = blockIdx.x * blockDim.x + threadIdx.x;
    if (i < n4) {
        float4 v = ((const float4*)in)[i];
        ushort4 o;
        o.x = f2bf(v.x); o.y = f2bf(v.y); o.z = f2bf(v.z); o.w = f2bf(v.w);
        ((ushort4*)out)[i] = o;
    }
}

// ---------------- kernel 0b: W [768][1536] fp32 -> Wt [1536][768] bf16 -----
__global__ void transpose_w_kernel(const float* __restrict__ W,
                                   unsigned short* __restrict__ Wt) {
    __shared__ float tile[32][33];
    int n0 = blockIdx.x * 32, k0 = blockIdx.y * 32;
    int tx = threadIdx.x & 31, ty = threadIdx.x >> 5;   // ty: 0..7
    #pragma unroll
    for (int r = 0; r < 32; r += 8)
        tile[ty + r][tx] = W[(k0 + ty + r) * 1536 + n0 + tx];   // tile[k_l][n_l]
    __syncthreads();
    #pragma unroll
    for (int r = 0; r < 32; r += 8)
        Wt[(n0 + ty + r) * 768 + k0 + tx] = f2bf(tile[tx][ty + r]);
}

// ---------------- kernel 0c: RoPE sin/cos tables [1024][32] ----------------
__global__ void rope_table_kernel(float* __restrict__ cosT, float* __restrict__ sinT) {
    int idx = blockIdx.x * blockDim.x + threadIdx.x;   // t*32 + i
    int t = idx >> 5, i = idx & 31;
    float inv = powf(10000.0f, -(float)i / 32.0f);     // 10000^(-2i/64)
    float ang = (float)t * inv;
    cosT[idx] = cosf(ang);
    sinT[idx] = sinf(ang);
}

// ---------------- kernel 1: proj GEMM + bias + RoPE -> q,k bf16 ------------
// A = hs_bf16 [8192][768], Bt = Wt_bf16 [1536][768]; C tile 128x128, BK=64.
// m97 structure: global_load_lds(16B) into linear [128][64] bf16 tiles, with
// both-sides chunk swizzle col16 ^= (row&7)  (16-way -> free 2-way on ds_read).
__global__ __launch_bounds__(256) void proj_rope_kernel(
    const unsigned short* __restrict__ A,
    const unsigned short* __restrict__ Bt,
    const float* __restrict__ bias,
    const float* __restrict__ cosT, const float* __restrict__ sinT,
    unsigned short* __restrict__ qout, unsigned short* __restrict__ kout)
{
    __shared__ unsigned short As[128 * 64];
    __shared__ unsigned short Bs[128 * 64];
    const int tid = threadIdx.x;
    const int lane = tid & 63, w = tid >> 6;
    const int wm = w >> 1, wn = w & 1;
    const int bm = blockIdx.y * 128, bn = blockIdx.x * 128;
    const int l15 = lane & 15, l4 = lane >> 4;

    // staging geometry: chunk c = i*256 + w*64 + lane; 16B chunks, 8 per row
    int crow[4], gcol[4], lbase[4];
    #pragma unroll
    for (int i = 0; i < 4; ++i) {
        int c = i * 256 + w * 64 + lane;
        crow[i] = c >> 3;                          // tile row 0..127
        gcol[i] = ((c & 7) ^ (crow[i] & 7)) * 8;   // pre-swizzled source col (bf16)
        lbase[i] = (i * 256 + w * 64) * 8;         // wave-uniform LDS ushort base
    }

    f32x4 acc[4][4] = {};
    const int swr = l15 & 7;   // row&7 for all fragment rows (wm*64+i*16 ≡ 0 mod 8)

    for (int k0 = 0; k0 < 768; k0 += 64) {
        __syncthreads();   // LDS reuse guard
        #pragma unroll
        for (int i = 0; i < 4; ++i) {
            gload_lds16(&A[(size_t)(bm + crow[i]) * 768 + k0 + gcol[i]], &As[lbase[i]]);
            gload_lds16(&Bt[(size_t)(bn + crow[i]) * 768 + k0 + gcol[i]], &Bs[lbase[i]]);
        }
        __syncthreads();   // drains vmcnt before ds_read
        #pragma unroll
        for (int ks = 0; ks < 2; ++ks) {
            bf16x8 af[4], bq[4];
            #pragma unroll
            for (int i = 0; i < 4; ++i) {
                const int ar = wm * 64 + i * 16 + l15;
                const int br = wn * 64 + i * 16 + l15;
                const int cc = (ks * 4 + l4) ^ swr;   // swizzled chunk col
                af[i] = *(const bf16x8*)&As[(ar * 8 + cc) * 8];
                bq[i] = *(const bf16x8*)&Bs[(br * 8 + cc) * 8];
            }
            #pragma unroll
            for (int i = 0; i < 4; ++i)
                #pragma unroll
                for (int j = 0; j < 4; ++j)
                    acc[i][j] = __builtin_amdgcn_mfma_f32_16x16x32_bf16(
                        af[i], bq[j], acc[i][j], 0, 0, 0);
        }
    }

    // epilogue: bias + RoPE (pair via shfl_xor lane^1) + scatter to q/k bf16
    const int rbase = bm + wm * 64 + l4 * 4;
    const int cbase = bn + wn * 64 + l15;
    #pragma unroll
    for (int mi = 0; mi < 4; ++mi) {
        #pragma unroll
        for (int ni = 0; ni < 4; ++ni) {
            const int n = cbase + ni * 16;
            const float bv = bias[n];
            const int h = n >> 7, ww = n & 127;
            const int d = ww & 63, fi = d >> 1;
            unsigned short* __restrict__ dst = (ww < 64) ? qout : kout;
            #pragma unroll
            for (int j = 0; j < 4; ++j) {
                const int m = rbase + mi * 16 + j;
                const int t = m & 1023, bb = m >> 10;
                float v = acc[mi][ni][j] + bv;
                float p = __shfl_xor(v, 1, 64);
                float c = cosT[t * 32 + fi], s = sinT[t * 32 + fi];
                float r = (d & 1) ? fmaf(v, c, p * s) : fmaf(v, c, -p * s);
                dst[((bb * 12 + h) * 1024 + t) * 64 + d] = f2bf(r);
            }
        }
    }
}

// ---------------- kernel 2: logits = q@k^T, mask, causal, scale ------------
// tn < tm blocks: output is bit-exactly independent of s (|s·mv| << half-ulp
// of the NEG-accumulated constant) -> pure float4 constant stores, no loads.
// Compute blocks: direct global->reg fragments (q/k are L2/L3-resident;
// LDS staging of cache-fit data is pure overhead).
__global__ __launch_bounds__(256) void logits_kernel(
    const unsigned short* __restrict__ q, const unsigned short* __restrict__ k,
    const int* __restrict__ mask, float* __restrict__ out)
{
    const int tid = threadIdx.x;
    const int tn = blockIdx.x, tm = blockIdx.y, z = blockIdx.z;  // z = b*12+h
    const int bb = z / 12;

    if (tn < tm) {
        // strictly-below-diagonal: value depends only on the column's mask
        const int c4 = (tid & 31) * 4;       // col offset in tile, 0..124
        const int r0 = tid >> 5;             // 0..7
        const int nb = tn * 128 + c4;
        float4 v;
        #pragma unroll
        for (int e = 0; e < 4; ++e) {
            float mv = (float)mask[bb * 1024 + nb + e];
            float addc = -(1.0f - mv) * NEG;
            ((float*)&v)[e] = (addc - NEG) * 0.125f;   // formula with s = 0
        }
        float* __restrict__ base = out + (size_t)(z * 1024 + tm * 128) * 1024 + nb;
        #pragma unroll
        for (int r = 0; r < 16; ++r)
            *(float4*)&base[(size_t)(r * 8 + r0) * 1024] = v;
        return;
    }

    const int lane = tid & 63, w = tid >> 6;
    const int wm = w >> 1, wn = w & 1;
    const int l15 = lane & 15, l4 = lane >> 4;

    f32x4 acc[4][4] = {};
    const unsigned short* __restrict__ qb = q + (size_t)(z * 1024 + tm * 128) * 64;
    const unsigned short* __restrict__ kb = k + (size_t)(z * 1024 + tn * 128) * 64;

    #pragma unroll
    for (int ks = 0; ks < 2; ++ks) {
        bf16x8 af[4], bq[4];
        #pragma unroll
        for (int i = 0; i < 4; ++i) {
            af[i] = *(const bf16x8*)&qb[(size_t)(wm * 64 + i * 16 + l15) * 64 + ks * 32 + l4 * 8];
            bq[i] = *(const bf16x8*)&kb[(size_t)(wn * 64 + i * 16 + l15) * 64 + ks * 32 + l4 * 8];
        }
        #pragma unroll
        for (int i = 0; i < 4; ++i)
            #pragma unroll
            for (int j = 0; j < 4; ++j)
                acc[i][j] = __builtin_amdgcn_mfma_f32_16x16x32_bf16(
                    af[i], bq[j], acc[i][j], 0, 0, 0);
    }

    const int rbase = tm * 128 + wm * 64 + l4 * 4;
    const int cbase = tn * 128 + wn * 64 + l15;
    float* __restrict__ po = out + (size_t)(z * 1024 + rbase) * 1024 + cbase;
    #pragma unroll
    for (int ni = 0; ni < 4; ++ni) {
        const int n = cbase + ni * 16;
        const float mv = (float)mask[bb * 1024 + n];
        const float addc = -(1.0f - mv) * NEG;
        #pragma unroll
        for (int mi = 0; mi < 4; ++mi) {
            #pragma unroll
            for (int j = 0; j < 4; ++j) {
                const int m = rbase + mi * 16 + j;
                float s = acc[mi][ni][j];
                po[(size_t)(mi * 16 + j) * 1024 + ni * 16] =
                    (s * mv + addc - (n < m ? NEG : 0.0f)) * 0.125f;
            }
        }
    }
}

extern "C" void kernel_launch(void* const* d_in, const int* in_sizes, int n_in,
                              void* d_out, int out_size, void* d_ws, size_t ws_size,
                              hipStream_t stream) {
    const float* hs   = (const float*)d_in[0];   // [8,1024,768] f32
    const int*   mask = (const int*)d_in[1];     // [8,1024] i32
    const float* W    = (const float*)d_in[2];   // [768,1536] f32
    const float* bias = (const float*)d_in[3];   // [1536] f32
    float* out = (float*)d_out;                  // [8,12,1024,1024] f32

    char* ws = (char*)d_ws;
    unsigned short* qbuf = (unsigned short*)(ws + 0);           // 12,582,912 B
    unsigned short* kbuf = (unsigned short*)(ws + 12582912);    // 12,582,912 B
    unsigned short* hsb  = (unsigned short*)(ws + 25165824);    // 12,582,912 B
    unsigned short* wtb  = (unsigned short*)(ws + 37748736);    //  2,359,296 B
    float* cosT = (float*)(ws + 40108032);                      //    131,072 B
    float* sinT = (float*)(ws + 40239104);                      //    131,072 B

    cvt_bf16_kernel<<<6291456 / 4 / 256, 256, 0, stream>>>(hs, hsb, 6291456 / 4);
    transpose_w_kernel<<<dim3(48, 24), 256, 0, stream>>>(W, wtb);
    rope_table_kernel<<<128, 256, 0, stream>>>(cosT, sinT);
    proj_rope_kernel<<<dim3(12, 64), 256, 0, stream>>>(hsb, wtb, bias, cosT, sinT,
                                                       qbuf, kbuf);
    logits_kernel<<<dim3(8, 8, 96), 256, 0, stream>>>(qbuf, kbuf, mask, out);
}

// Round 5
// 501.366 us; speedup vs baseline: 1.0522x; 1.0522x over previous
//
#include <hip/hip_runtime.h>

#define NEG 1000000000000.0f

typedef __attribute__((ext_vector_type(4))) float f32x4;
typedef __attribute__((ext_vector_type(8))) short bf16x8;

__device__ __forceinline__ unsigned short f2bf(float f) {
    union { float f; unsigned u; } a;
    a.f = f;
    unsigned u = a.u;
    return (unsigned short)((u + 0x7FFFu + ((u >> 16) & 1u)) >> 16);
}

// async global->LDS, 16B per lane, wave-uniform LDS base
__device__ __forceinline__ void gload_lds16(const void* g, void* l) {
    __builtin_amdgcn_global_load_lds(
        (const __attribute__((address_space(1))) unsigned int*)g,
        (__attribute__((address_space(3))) unsigned int*)l, 16, 0, 0);
}

// ---------------- kernel 0a: fp32 -> bf16 convert (hidden_states) ----------
__global__ void cvt_bf16_kernel(const float* __restrict__ in,
                                unsigned short* __restrict__ out, int n4) {
    int i = blockIdx.x * blockDim.x + threadIdx.x;
    if (i < n4) {
        float4 v = ((const float4*)in)[i];
        ushort4 o;
        o.x = f2bf(v.x); o.y = f2bf(v.y); o.z = f2bf(v.z); o.w = f2bf(v.w);
        ((ushort4*)out)[i] = o;
    }
}

// ---------------- kernel 0b: W [768][1536] fp32 -> Wt [1536][768] bf16 -----
__global__ void transpose_w_kernel(const float* __restrict__ W,
                                   unsigned short* __restrict__ Wt) {
    __shared__ float tile[32][33];
    int n0 = blockIdx.x * 32, k0 = blockIdx.y * 32;
    int tx = threadIdx.x & 31, ty = threadIdx.x >> 5;   // ty: 0..7
    #pragma unroll
    for (int r = 0; r < 32; r += 8)
        tile[ty + r][tx] = W[(k0 + ty + r) * 1536 + n0 + tx];   // tile[k_l][n_l]
    __syncthreads();
    #pragma unroll
    for (int r = 0; r < 32; r += 8)
        Wt[(n0 + ty + r) * 768 + k0 + tx] = f2bf(tile[tx][ty + r]);
}

// ---------------- kernel 0c: RoPE sin/cos tables [1024][32] ----------------
__global__ void rope_table_kernel(float* __restrict__ cosT, float* __restrict__ sinT) {
    int idx = blockIdx.x * blockDim.x + threadIdx.x;   // t*32 + i
    int t = idx >> 5, i = idx & 31;
    float inv = powf(10000.0f, -(float)i / 32.0f);     // 10000^(-2i/64)
    float ang = (float)t * inv;
    cosT[idx] = cosf(ang);
    sinT[idx] = sinf(ang);
}

// ---------------- kernel 1: proj GEMM + bias + RoPE -> q,k bf16 ------------
// A = hs_bf16 [8192][768], Bt = Wt_bf16 [1536][768]; C tile 128x128, BK=64.
// m97 structure: global_load_lds(16B) into linear [128][64] bf16 tiles, with
// both-sides chunk swizzle col16 ^= (row&7)  (16-way -> free 2-way on ds_read).
__global__ __launch_bounds__(256) void proj_rope_kernel(
    const unsigned short* __restrict__ A,
    const unsigned short* __restrict__ Bt,
    const float* __restrict__ bias,
    const float* __restrict__ cosT, const float* __restrict__ sinT,
    unsigned short* __restrict__ qout, unsigned short* __restrict__ kout)
{
    __shared__ unsigned short As[128 * 64];
    __shared__ unsigned short Bs[128 * 64];
    const int tid = threadIdx.x;
    const int lane = tid & 63, w = tid >> 6;
    const int wm = w >> 1, wn = w & 1;
    const int bm = blockIdx.y * 128, bn = blockIdx.x * 128;
    const int l15 = lane & 15, l4 = lane >> 4;

    // staging geometry: chunk c = i*256 + w*64 + lane; 16B chunks, 8 per row
    int crow[4], gcol[4], lbase[4];
    #pragma unroll
    for (int i = 0; i < 4; ++i) {
        int c = i * 256 + w * 64 + lane;
        crow[i] = c >> 3;                          // tile row 0..127
        gcol[i] = ((c & 7) ^ (crow[i] & 7)) * 8;   // pre-swizzled source col (bf16)
        lbase[i] = (i * 256 + w * 64) * 8;         // wave-uniform LDS ushort base
    }

    f32x4 acc[4][4] = {};
    const int swr = l15 & 7;   // row&7 for all fragment rows (wm*64+i*16 ≡ 0 mod 8)

    for (int k0 = 0; k0 < 768; k0 += 64) {
        __syncthreads();   // LDS reuse guard
        #pragma unroll
        for (int i = 0; i < 4; ++i) {
            gload_lds16(&A[(size_t)(bm + crow[i]) * 768 + k0 + gcol[i]], &As[lbase[i]]);
            gload_lds16(&Bt[(size_t)(bn + crow[i]) * 768 + k0 + gcol[i]], &Bs[lbase[i]]);
        }
        __syncthreads();   // drains vmcnt before ds_read
        #pragma unroll
        for (int ks = 0; ks < 2; ++ks) {
            bf16x8 af[4], bq[4];
            #pragma unroll
            for (int i = 0; i < 4; ++i) {
                const int ar = wm * 64 + i * 16 + l15;
                const int br = wn * 64 + i * 16 + l15;
                const int cc = (ks * 4 + l4) ^ swr;   // swizzled chunk col
                af[i] = *(const bf16x8*)&As[(ar * 8 + cc) * 8];
                bq[i] = *(const bf16x8*)&Bs[(br * 8 + cc) * 8];
            }
            #pragma unroll
            for (int i = 0; i < 4; ++i)
                #pragma unroll
                for (int j = 0; j < 4; ++j)
                    acc[i][j] = __builtin_amdgcn_mfma_f32_16x16x32_bf16(
                        af[i], bq[j], acc[i][j], 0, 0, 0);
        }
    }

    // epilogue: bias + RoPE (pair via shfl_xor lane^1) + scatter to q/k bf16
    const int rbase = bm + wm * 64 + l4 * 4;
    const int cbase = bn + wn * 64 + l15;
    #pragma unroll
    for (int mi = 0; mi < 4; ++mi) {
        #pragma unroll
        for (int ni = 0; ni < 4; ++ni) {
            const int n = cbase + ni * 16;
            const float bv = bias[n];
            const int h = n >> 7, ww = n & 127;
            const int d = ww & 63, fi = d >> 1;
            unsigned short* __restrict__ dst = (ww < 64) ? qout : kout;
            #pragma unroll
            for (int j = 0; j < 4; ++j) {
                const int m = rbase + mi * 16 + j;
                const int t = m & 1023, bb = m >> 10;
                float v = acc[mi][ni][j] + bv;
                float p = __shfl_xor(v, 1, 64);
                float c = cosT[t * 32 + fi], s = sinT[t * 32 + fi];
                float r = (d & 1) ? fmaf(v, c, p * s) : fmaf(v, c, -p * s);
                dst[((bb * 12 + h) * 1024 + t) * 64 + d] = f2bf(r);
            }
        }
    }
}

// ---------------- kernel 2: logits = q@k^T, mask, causal, scale ------------
// tn < tm blocks: output is bit-exactly independent of s -> pure float4
// constant stores. Compute blocks: global->reg fragments (q/k L2/L3-resident),
// epilogue transposed through wave-private LDS so stores are dwordx4
// (16 store instrs/thread instead of 64 scalar ones -> 4x less store issue).
__global__ __launch_bounds__(256) void logits_kernel(
    const unsigned short* __restrict__ q, const unsigned short* __restrict__ k,
    const int* __restrict__ mask, float* __restrict__ out)
{
    const int tid = threadIdx.x;
    const int tn = blockIdx.x, tm = blockIdx.y, z = blockIdx.z;  // z = b*12+h
    const int bb = z / 12;

    if (tn < tm) {
        // strictly-below-diagonal: value depends only on the column's mask
        const int c4 = (tid & 31) * 4;       // col offset in tile, 0..124
        const int r0 = tid >> 5;             // 0..7
        const int nb = tn * 128 + c4;
        float4 v;
        #pragma unroll
        for (int e = 0; e < 4; ++e) {
            float mv = (float)mask[bb * 1024 + nb + e];
            float addc = -(1.0f - mv) * NEG;
            ((float*)&v)[e] = (addc - NEG) * 0.125f;   // formula with s = 0
        }
        float* __restrict__ base = out + (size_t)(z * 1024 + tm * 128) * 1024 + nb;
        #pragma unroll
        for (int r = 0; r < 16; ++r)
            *(float4*)&base[(size_t)(r * 8 + r0) * 1024] = v;
        return;
    }

    __shared__ float tr[4][16][68];   // wave-private 16x64 stripe, +4 pad
    const int lane = tid & 63, w = tid >> 6;
    const int wm = w >> 1, wn = w & 1;
    const int l15 = lane & 15, l4 = lane >> 4;

    f32x4 acc[4][4] = {};
    const unsigned short* __restrict__ qb = q + (size_t)(z * 1024 + tm * 128) * 64;
    const unsigned short* __restrict__ kb = k + (size_t)(z * 1024 + tn * 128) * 64;

    #pragma unroll
    for (int ks = 0; ks < 2; ++ks) {
        bf16x8 af[4], bq[4];
        #pragma unroll
        for (int i = 0; i < 4; ++i) {
            af[i] = *(const bf16x8*)&qb[(size_t)(wm * 64 + i * 16 + l15) * 64 + ks * 32 + l4 * 8];
            bq[i] = *(const bf16x8*)&kb[(size_t)(wn * 64 + i * 16 + l15) * 64 + ks * 32 + l4 * 8];
        }
        #pragma unroll
        for (int i = 0; i < 4; ++i)
            #pragma unroll
            for (int j = 0; j < 4; ++j)
                acc[i][j] = __builtin_amdgcn_mfma_f32_16x16x32_bf16(
                    af[i], bq[j], acc[i][j], 0, 0, 0);
    }

    // epilogue: mask/causal/scale in fragment layout, transpose via LDS,
    // store dwordx4 (wave covers 4 rows x 256B contiguous per instr)
    const int rw = tm * 128 + wm * 64;   // wave row base (global m)
    const int cw = tn * 128 + wn * 64;   // wave col base (global n)
    float mv[4], addc[4];
    int ncol[4];
    #pragma unroll
    for (int ni = 0; ni < 4; ++ni) {
        ncol[ni] = cw + ni * 16 + l15;
        mv[ni] = (float)mask[bb * 1024 + ncol[ni]];
        addc[ni] = -(1.0f - mv[ni]) * NEG;
    }
    float* __restrict__ outz = out + (size_t)z * 1024 * 1024;
    #pragma unroll
    for (int mi = 0; mi < 4; ++mi) {
        #pragma unroll
        for (int ni = 0; ni < 4; ++ni)
            #pragma unroll
            for (int j = 0; j < 4; ++j) {
                const int m = rw + mi * 16 + l4 * 4 + j;
                float s = acc[mi][ni][j];
                tr[w][l4 * 4 + j][ni * 16 + l15] =
                    (s * mv[ni] + addc[ni] - (ncol[ni] < m ? NEG : 0.0f)) * 0.125f;
            }
        __syncthreads();
        #pragma unroll
        for (int ri = 0; ri < 4; ++ri) {
            float4 vv = *(const float4*)&tr[w][ri * 4 + l4][l15 * 4];
            *(float4*)&outz[(size_t)(rw + mi * 16 + ri * 4 + l4) * 1024 + cw + l15 * 4] = vv;
        }
        __syncthreads();
    }
}

extern "C" void kernel_launch(void* const* d_in, const int* in_sizes, int n_in,
                              void* d_out, int out_size, void* d_ws, size_t ws_size,
                              hipStream_t stream) {
    const float* hs   = (const float*)d_in[0];   // [8,1024,768] f32
    const int*   mask = (const int*)d_in[1];     // [8,1024] i32
    const float* W    = (const float*)d_in[2];   // [768,1536] f32
    const float* bias = (const float*)d_in[3];   // [1536] f32
    float* out = (float*)d_out;                  // [8,12,1024,1024] f32

    char* ws = (char*)d_ws;
    unsigned short* qbuf = (unsigned short*)(ws + 0);           // 12,582,912 B
    unsigned short* kbuf = (unsigned short*)(ws + 12582912);    // 12,582,912 B
    unsigned short* hsb  = (unsigned short*)(ws + 25165824);    // 12,582,912 B
    unsigned short* wtb  = (unsigned short*)(ws + 37748736);    //  2,359,296 B
    float* cosT = (float*)(ws + 40108032);                      //    131,072 B
    float* sinT = (float*)(ws + 40239104);                      //    131,072 B

    cvt_bf16_kernel<<<6291456 / 4 / 256, 256, 0, stream>>>(hs, hsb, 6291456 / 4);
    transpose_w_kernel<<<dim3(48, 24), 256, 0, stream>>>(W, wtb);
    rope_table_kernel<<<128, 256, 0, stream>>>(cosT, sinT);
    proj_rope_kernel<<<dim3(12, 64), 256, 0, stream>>>(hsb, wtb, bias, cosT, sinT,
                                                       qbuf, kbuf);
    logits_kernel<<<dim3(8, 8, 96), 256, 0, stream>>>(qbuf, kbuf, mask, out);
}

// Round 8
// 494.294 us; speedup vs baseline: 1.0673x; 1.0143x over previous
//
#include <hip/hip_runtime.h>

#define NEG 1000000000000.0f

typedef __attribute__((ext_vector_type(4))) float f32x4;
typedef __attribute__((ext_vector_type(8))) short bf16x8;
typedef __attribute__((ext_vector_type(8))) unsigned short u16x8;

__device__ __forceinline__ unsigned short f2bf(float f) {
    union { float f; unsigned u; } a;
    a.f = f;
    unsigned u = a.u;
    return (unsigned short)((u + 0x7FFFu + ((u >> 16) & 1u)) >> 16);
}

// async global->LDS, 16B per lane, wave-uniform LDS base
__device__ __forceinline__ void gload_lds16(const void* g, void* l) {
    __builtin_amdgcn_global_load_lds(
        (const __attribute__((address_space(1))) unsigned int*)g,
        (__attribute__((address_space(3))) unsigned int*)l, 16, 0, 0);
}

// wave-private LDS write->read fence (no cross-wave sharing -> no s_barrier)
__device__ __forceinline__ void lds_fence() {
    asm volatile("s_waitcnt lgkmcnt(0)" ::: "memory");
    __builtin_amdgcn_sched_barrier(0);
}

// ---------------- kernel 0a: fp32 -> bf16 convert (hidden_states) ----------
__global__ void cvt_bf16_kernel(const float* __restrict__ in,
                                unsigned short* __restrict__ out, int n4) {
    int i = blockIdx.x * blockDim.x + threadIdx.x;
    if (i < n4) {
        float4 v = ((const float4*)in)[i];
        ushort4 o;
        o.x = f2bf(v.x); o.y = f2bf(v.y); o.z = f2bf(v.z); o.w = f2bf(v.w);
        ((ushort4*)out)[i] = o;
    }
}

// ---------------- kernel 0b: W [768][1536] fp32 -> Wt [1536][768] bf16 -----
__global__ void transpose_w_kernel(const float* __restrict__ W,
                                   unsigned short* __restrict__ Wt) {
    __shared__ float tile[32][33];
    int n0 = blockIdx.x * 32, k0 = blockIdx.y * 32;
    int tx = threadIdx.x & 31, ty = threadIdx.x >> 5;   // ty: 0..7
    #pragma unroll
    for (int r = 0; r < 32; r += 8)
        tile[ty + r][tx] = W[(k0 + ty + r) * 1536 + n0 + tx];   // tile[k_l][n_l]
    __syncthreads();
    #pragma unroll
    for (int r = 0; r < 32; r += 8)
        Wt[(n0 + ty + r) * 768 + k0 + tx] = f2bf(tile[tx][ty + r]);
}

// ---------------- kernel 0c: RoPE sin/cos tables [1024][32] ----------------
__global__ void rope_table_kernel(float* __restrict__ cosT, float* __restrict__ sinT) {
    int idx = blockIdx.x * blockDim.x + threadIdx.x;   // t*32 + i
    int t = idx >> 5, i = idx & 31;
    float inv = powf(10000.0f, -(float)i / 32.0f);     // 10000^(-2i/64)
    float ang = (float)t * inv;
    cosT[idx] = cosf(ang);
    sinT[idx] = sinf(ang);
}

// ---------------- kernel 1: proj GEMM + bias + RoPE -> q,k bf16 ------------
// A = hs_bf16 [8192][768], Bt = Wt_bf16 [1536][768]; C tile 128x128, BK=64.
// Staging: global_load_lds(16B) into linear [128][64] bf16 tiles, both-sides
// chunk swizzle. Epilogue: per-wave LDS transpose (block x = one head; wave
// covers its full 64-d q or k segment) -> in-register RoPE pairs + ushort8
// stores (8 wide stores/thread instead of 64 scalar + 64 shfl).
__global__ __launch_bounds__(256) void proj_rope_kernel(
    const unsigned short* __restrict__ A,
    const unsigned short* __restrict__ Bt,
    const float* __restrict__ bias,
    const float* __restrict__ cosT, const float* __restrict__ sinT,
    unsigned short* __restrict__ qout, unsigned short* __restrict__ kout)
{
    __shared__ unsigned short As[128 * 64];
    __shared__ unsigned short Bs[128 * 64];
    __shared__ float trp[4][16][68];   // per-wave 16x64 f32 transpose stripe
    const int tid = threadIdx.x;
    const int lane = tid & 63, w = tid >> 6;
    const int wm = w >> 1, wn = w & 1;
    const int bm = blockIdx.y * 128, bn = blockIdx.x * 128;
    const int l15 = lane & 15, l4 = lane >> 4;

    // staging geometry: chunk c = i*256 + w*64 + lane; 16B chunks, 8 per row
    int crow[4], gcol[4], lbase[4];
    #pragma unroll
    for (int i = 0; i < 4; ++i) {
        int c = i * 256 + w * 64 + lane;
        crow[i] = c >> 3;                          // tile row 0..127
        gcol[i] = ((c & 7) ^ (crow[i] & 7)) * 8;   // pre-swizzled source col (bf16)
        lbase[i] = (i * 256 + w * 64) * 8;         // wave-uniform LDS ushort base
    }

    f32x4 acc[4][4] = {};
    const int swr = l15 & 7;   // row&7 for all fragment rows (wm*64+i*16 ≡ 0 mod 8)

    for (int k0 = 0; k0 < 768; k0 += 64) {
        __syncthreads();   // LDS reuse guard
        #pragma unroll
        for (int i = 0; i < 4; ++i) {
            gload_lds16(&A[(size_t)(bm + crow[i]) * 768 + k0 + gcol[i]], &As[lbase[i]]);
            gload_lds16(&Bt[(size_t)(bn + crow[i]) * 768 + k0 + gcol[i]], &Bs[lbase[i]]);
        }
        __syncthreads();   // drains vmcnt before ds_read
        #pragma unroll
        for (int ks = 0; ks < 2; ++ks) {
            bf16x8 af[4], bq[4];
            #pragma unroll
            for (int i = 0; i < 4; ++i) {
                const int ar = wm * 64 + i * 16 + l15;
                const int br = wn * 64 + i * 16 + l15;
                const int cc = (ks * 4 + l4) ^ swr;   // swizzled chunk col
                af[i] = *(const bf16x8*)&As[(ar * 8 + cc) * 8];
                bq[i] = *(const bf16x8*)&Bs[(br * 8 + cc) * 8];
            }
            #pragma unroll
            for (int i = 0; i < 4; ++i)
                #pragma unroll
                for (int j = 0; j < 4; ++j)
                    acc[i][j] = __builtin_amdgcn_mfma_f32_16x16x32_bf16(
                        af[i], bq[j], acc[i][j], 0, 0, 0);
        }
    }

    // epilogue: wave holds C 64x64 = (64 t-rows) x (full 64-d q|k of head h)
    const int h = blockIdx.x;          // grid.x = 12 heads
    const int bbq = bm >> 10;          // batch (block never crosses t=1024)
    const int tbase = bm & 1023;
    unsigned short* __restrict__ dstb =
        ((wn == 0) ? qout : kout) + (size_t)(bbq * 12 + h) * 1024 * 64;
    float bv[4];
    #pragma unroll
    for (int ni = 0; ni < 4; ++ni) bv[ni] = bias[bn + wn * 64 + ni * 16 + l15];

    #pragma unroll
    for (int mi = 0; mi < 4; ++mi) {
        #pragma unroll
        for (int ni = 0; ni < 4; ++ni)
            #pragma unroll
            for (int j = 0; j < 4; ++j)
                trp[w][l4 * 4 + j][ni * 16 + l15] = acc[mi][ni][j] + bv[ni];
        lds_fence();
        #pragma unroll
        for (int ps = 0; ps < 2; ++ps) {
            const int tl = ps * 8 + (lane >> 3);
            const int d0 = (lane & 7) * 8;
            const int tg = tbase + wm * 64 + mi * 16 + tl;
            float4 va = *(const float4*)&trp[w][tl][d0];
            float4 vb = *(const float4*)&trp[w][tl][d0 + 4];
            float4 cs = *(const float4*)&cosT[tg * 32 + (d0 >> 1)];
            float4 sn = *(const float4*)&sinT[tg * 32 + (d0 >> 1)];
            u16x8 o8;
            o8[0] = f2bf(fmaf(va.x, cs.x, -va.y * sn.x));
            o8[1] = f2bf(fmaf(va.y, cs.x,  va.x * sn.x));
            o8[2] = f2bf(fmaf(va.z, cs.y, -va.w * sn.y));
            o8[3] = f2bf(fmaf(va.w, cs.y,  va.z * sn.y));
            o8[4] = f2bf(fmaf(vb.x, cs.z, -vb.y * sn.z));
            o8[5] = f2bf(fmaf(vb.y, cs.z,  vb.x * sn.z));
            o8[6] = f2bf(fmaf(vb.z, cs.w, -vb.w * sn.w));
            o8[7] = f2bf(fmaf(vb.w, cs.w,  vb.z * sn.w));
            *(u16x8*)&dstb[(size_t)tg * 64 + d0] = o8;
        }
        lds_fence();   // reads done before next mi overwrites (in-order DS pipe)
    }
}

// ---------------- kernel 2: logits = q@k^T, mask, causal, scale ------------
// tn < tm blocks: output is bit-exactly independent of s -> pure float4
// constant stores. Compute blocks: global->reg fragments (q/k L2/L3-resident),
// epilogue transposed through wave-private LDS (no barriers: lgkmcnt fence
// only) so stores are dwordx4.
__global__ __launch_bounds__(256) void logits_kernel(
    const unsigned short* __restrict__ q, const unsigned short* __restrict__ k,
    const int* __restrict__ mask, float* __restrict__ out)
{
    const int tid = threadIdx.x;
    const int tn = blockIdx.x, tm = blockIdx.y, z = blockIdx.z;  // z = b*12+h
    const int bb = z / 12;

    if (tn < tm) {
        // strictly-below-diagonal: value depends only on the column's mask
        const int c4 = (tid & 31) * 4;       // col offset in tile, 0..124
        const int r0 = tid >> 5;             // 0..7
        const int nb = tn * 128 + c4;
        float4 v;
        #pragma unroll
        for (int e = 0; e < 4; ++e) {
            float mv = (float)mask[bb * 1024 + nb + e];
            float addc = -(1.0f - mv) * NEG;
            ((float*)&v)[e] = (addc - NEG) * 0.125f;   // formula with s = 0
        }
        float* __restrict__ base = out + (size_t)(z * 1024 + tm * 128) * 1024 + nb;
        #pragma unroll
        for (int r = 0; r < 16; ++r)
            *(float4*)&base[(size_t)(r * 8 + r0) * 1024] = v;
        return;
    }

    __shared__ float tr[4][16][68];   // wave-private 16x64 stripe, +4 pad
    const int lane = tid & 63, w = tid >> 6;
    const int wm = w >> 1, wn = w & 1;
    const int l15 = lane & 15, l4 = lane >> 4;

    f32x4 acc[4][4] = {};
    const unsigned short* __restrict__ qb = q + (size_t)(z * 1024 + tm * 128) * 64;
    const unsigned short* __restrict__ kb = k + (size_t)(z * 1024 + tn * 128) * 64;

    #pragma unroll
    for (int ks = 0; ks < 2; ++ks) {
        bf16x8 af[4], bq[4];
        #pragma unroll
        for (int i = 0; i < 4; ++i) {
            af[i] = *(const bf16x8*)&qb[(size_t)(wm * 64 + i * 16 + l15) * 64 + ks * 32 + l4 * 8];
            bq[i] = *(const bf16x8*)&kb[(size_t)(wn * 64 + i * 16 + l15) * 64 + ks * 32 + l4 * 8];
        }
        #pragma unroll
        for (int i = 0; i < 4; ++i)
            #pragma unroll
            for (int j = 0; j < 4; ++j)
                acc[i][j] = __builtin_amdgcn_mfma_f32_16x16x32_bf16(
                    af[i], bq[j], acc[i][j], 0, 0, 0);
    }

    // epilogue: mask/causal/scale in fragment layout, transpose via LDS,
    // store dwordx4 (wave covers 4 rows x 256B contiguous per instr)
    const int rw = tm * 128 + wm * 64;   // wave row base (global m)
    const int cw = tn * 128 + wn * 64;   // wave col base (global n)
    float mv[4], addc[4];
    int ncol[4];
    #pragma unroll
    for (int ni = 0; ni < 4; ++ni) {
        ncol[ni] = cw + ni * 16 + l15;
        mv[ni] = (float)mask[bb * 1024 + ncol[ni]];
        addc[ni] = -(1.0f - mv[ni]) * NEG;
    }
    float* __restrict__ outz = out + (size_t)z * 1024 * 1024;
    #pragma unroll
    for (int mi = 0; mi < 4; ++mi) {
        #pragma unroll
        for (int ni = 0; ni < 4; ++ni)
            #pragma unroll
            for (int j = 0; j < 4; ++j) {
                const int m = rw + mi * 16 + l4 * 4 + j;
                float s = acc[mi][ni][j];
                tr[w][l4 * 4 + j][ni * 16 + l15] =
                    (s * mv[ni] + addc[ni] - (ncol[ni] < m ? NEG : 0.0f)) * 0.125f;
            }
        lds_fence();
        #pragma unroll
        for (int ri = 0; ri < 4; ++ri) {
            float4 vv = *(const float4*)&tr[w][ri * 4 + l4][l15 * 4];
            *(float4*)&outz[(size_t)(rw + mi * 16 + ri * 4 + l4) * 1024 + cw + l15 * 4] = vv;
        }
        lds_fence();   // reads done before next mi overwrites
    }
}

extern "C" void kernel_launch(void* const* d_in, const int* in_sizes, int n_in,
                              void* d_out, int out_size, void* d_ws, size_t ws_size,
                              hipStream_t stream) {
    const float* hs   = (const float*)d_in[0];   // [8,1024,768] f32
    const int*   mask = (const int*)d_in[1];     // [8,1024] i32
    const float* W    = (const float*)d_in[2];   // [768,1536] f32
    const float* bias = (const float*)d_in[3];   // [1536] f32
    float* out = (float*)d_out;                  // [8,12,1024,1024] f32

    char* ws = (char*)d_ws;
    unsigned short* qbuf = (unsigned short*)(ws + 0);           // 12,582,912 B
    unsigned short* kbuf = (unsigned short*)(ws + 12582912);    // 12,582,912 B
    unsigned short* hsb  = (unsigned short*)(ws + 25165824);    // 12,582,912 B
    unsigned short* wtb  = (unsigned short*)(ws + 37748736);    //  2,359,296 B
    float* cosT = (float*)(ws + 40108032);                      //    131,072 B
    float* sinT = (float*)(ws + 40239104);                      //    131,072 B

    cvt_bf16_kernel<<<6291456 / 4 / 256, 256, 0, stream>>>(hs, hsb, 6291456 / 4);
    transpose_w_kernel<<<dim3(48, 24), 256, 0, stream>>>(W, wtb);
    rope_table_kernel<<<128, 256, 0, stream>>>(cosT, sinT);
    proj_rope_kernel<<<dim3(12, 64), 256, 0, stream>>>(hsb, wtb, bias, cosT, sinT,
                                                       qbuf, kbuf);
    logits_kernel<<<dim3(8, 8, 96), 256, 0, stream>>>(qbuf, kbuf, mask, out);
}